// Round 2
// baseline (135.332 us; speedup 1.0000x reference)
//
#include <hip/hip_runtime.h>
#include <hip/hip_bf16.h>

typedef __attribute__((ext_vector_type(8))) short short8;
typedef __attribute__((ext_vector_type(4))) float f32x4;

#define M_TOTAL 131072
#define K_DIM 512
#define N_DIM 128
#define HALF 65536
#define GBLOCKS 1024

__device__ __forceinline__ short bf16_bits(float f) {
    __hip_bfloat16 h = __float2bfloat16(f);
    return __builtin_bit_cast(short, h);
}

__device__ __forceinline__ short8 cvt8(f32x4 a, f32x4 b) {
    short8 p;
    p[0] = bf16_bits(a[0]); p[1] = bf16_bits(a[1]);
    p[2] = bf16_bits(a[2]); p[3] = bf16_bits(a[3]);
    p[4] = bf16_bits(b[0]); p[5] = bf16_bits(b[1]);
    p[6] = bf16_bits(b[2]); p[7] = bf16_bits(b[3]);
    return p;
}

// ---------------- W -> W^T bf16 prep ----------------------------------------
__global__ void __launch_bounds__(256) wt_prep_kernel(
    const float* __restrict__ W, __hip_bfloat16* __restrict__ Wt)
{
    int idx = blockIdx.x * 256 + threadIdx.x;   // 65536 total
    int k = idx >> 7;        // 0..511
    int n = idx & 127;       // 0..127
    Wt[n * K_DIM + k] = __float2bfloat16(W[idx]);
}

// ---- fused: out = relu(x@W + b) via barrier-free MFMA, + in-block MMD ------
// Block i owns first-half rows [64i,64i+64) (waves 0,1) and second-half rows
// [HALF+64i, HALF+64i+64) (waves 2,3). Each wave: 32 rows x 128 cols.
__global__ void __launch_bounds__(256) gemm_relu_mmd_kernel(
    const float* __restrict__ x, const __hip_bfloat16* __restrict__ Wt,
    const float* __restrict__ bias, float* __restrict__ out,
    double* __restrict__ partials)
{
    __shared__ float gsh[32];
    const int tid  = threadIdx.x;
    const int lane = tid & 63;
    const int wave = tid >> 6;
    const int frow = lane & 15;          // A row / B col within frag
    const int kg   = (lane >> 4) * 8;    // k-group offset
    const long blk = blockIdx.x;
    const long rowbase = (long)(wave >> 1) * HALF + blk * 64 + (long)(wave & 1) * 32;

    const float* pa0 = x + (rowbase + frow) * (long)K_DIM + kg;
    const float* pa1 = pa0 + 16 * K_DIM;
    const __hip_bfloat16* pb = Wt + (long)frow * K_DIM + kg;

    f32x4 acc[2][8];
#pragma unroll
    for (int m = 0; m < 2; ++m)
#pragma unroll
        for (int n = 0; n < 8; ++n) acc[m][n] = (f32x4)(0.0f);

#pragma unroll 2
    for (int kt = 0; kt < K_DIM; kt += 32) {
        f32x4 x00 = __builtin_nontemporal_load((const f32x4*)(pa0 + kt));
        f32x4 x01 = __builtin_nontemporal_load((const f32x4*)(pa0 + kt + 4));
        f32x4 x10 = __builtin_nontemporal_load((const f32x4*)(pa1 + kt));
        f32x4 x11 = __builtin_nontemporal_load((const f32x4*)(pa1 + kt + 4));
        short8 bfv[8];
#pragma unroll
        for (int n = 0; n < 8; ++n)
            bfv[n] = *(const short8*)(pb + (long)n * 16 * K_DIM + kt);
        short8 a0 = cvt8(x00, x01);
        short8 a1 = cvt8(x10, x11);
#pragma unroll
        for (int n = 0; n < 8; ++n) {
            acc[0][n] = __builtin_amdgcn_mfma_f32_16x16x32_bf16(a0, bfv[n], acc[0][n], 0, 0, 0);
            acc[1][n] = __builtin_amdgcn_mfma_f32_16x16x32_bf16(a1, bfv[n], acc[1][n], 0, 0, 0);
        }
    }

    // epilogue: bias + relu + store. C/D: col=lane&15, row=(lane>>4)*4+reg
    float bv[8];
#pragma unroll
    for (int n = 0; n < 8; ++n) bv[n] = bias[n * 16 + frow];
    const long rowq = rowbase + ((lane >> 4) * 4);
#pragma unroll
    for (int m = 0; m < 2; ++m)
#pragma unroll
        for (int j = 0; j < 4; ++j) {
            float* orow = out + (rowq + m * 16 + j) * N_DIM;
#pragma unroll
            for (int n = 0; n < 8; ++n)
                orow[n * 16 + frow] = fmaxf(acc[m][n][j] + bv[n], 0.0f);
        }

    // ---- in-block MMD over the 32 pairs this block owns --------------------
    __threadfence_block();
    __syncthreads();

    const int pr  = tid >> 3;      // pair 0..31
    const int sub = tid & 7;       // 8 threads/pair, 16 dims each
    const long p  = blk * 32 + pr;
    const float* r0 = out + (2 * p) * (long)N_DIM + sub * 16;          // s0
    const float* r1 = r0 + N_DIM;                                      // s1
    const float* r2 = out + ((long)HALF + 2 * p) * (long)N_DIM + sub * 16; // t0
    const float* r3 = r2 + N_DIM;                                      // t1

    f32x4 vss = (f32x4)(0.f), vtt = (f32x4)(0.f), vst = (f32x4)(0.f), vts = (f32x4)(0.f);
#pragma unroll
    for (int c = 0; c < 4; ++c) {
        f32x4 a0 = *(const f32x4*)(r0 + 4 * c);
        f32x4 a1 = *(const f32x4*)(r1 + 4 * c);
        f32x4 b0 = *(const f32x4*)(r2 + 4 * c);
        f32x4 b1 = *(const f32x4*)(r3 + 4 * c);
        f32x4 d;
        d = a0 - a1; vss += d * d;
        d = b0 - b1; vtt += d * d;
        d = a0 - b1; vst += d * d;
        d = a1 - b0; vts += d * d;
    }
    float D[4];
    D[0] = vss[0] + vss[1] + vss[2] + vss[3];
    D[1] = vtt[0] + vtt[1] + vtt[2] + vtt[3];
    D[2] = vst[0] + vst[1] + vst[2] + vst[3];
    D[3] = vts[0] + vts[1] + vts[2] + vts[3];
#pragma unroll
    for (int off = 1; off <= 4; off <<= 1) {
#pragma unroll
        for (int i = 0; i < 4; ++i) D[i] += __shfl_xor(D[i], off, 64);
    }
    // 32 exp terms (4 distances x 8 gammas) spread over the 8 threads
    float part = 0.f;
#pragma unroll
    for (int j = 0; j < 4; ++j) {
        const int t  = sub * 4 + j;
        const int di = t >> 3;           // 0..3
        const int k  = t & 7;            // gamma index
        const float invg = 16.0f / (float)(1 << k);   // 1/gamma_k
        const float e = expf(-D[di] * invg);
        part += (di < 2) ? e : -e;
    }
#pragma unroll
    for (int off = 1; off <= 4; off <<= 1) part += __shfl_xor(part, off, 64);
    if (sub == 0) gsh[pr] = part * 0.125f;
    __syncthreads();
    if (tid == 0) {
        double s = 0.0;
#pragma unroll
        for (int i = 0; i < 32; ++i) s += (double)gsh[i];
        partials[blk] = s;
    }
}

__global__ void __launch_bounds__(256) mmd_reduce_kernel(
    const double* __restrict__ partials, float* __restrict__ loss)
{
    __shared__ double sd[256];
    const int tid = threadIdx.x;
    double s = 0.0;
    for (int i = tid; i < GBLOCKS; i += 256) s += partials[i];
    sd[tid] = s;
    __syncthreads();
    for (int w = 128; w; w >>= 1) {
        if (tid < w) sd[tid] += sd[tid + w];
        __syncthreads();
    }
    if (tid == 0) loss[0] = (float)(sd[0] * (2.0 / 65536.0));
}

extern "C" void kernel_launch(void* const* d_in, const int* in_sizes, int n_in,
                              void* d_out, int out_size, void* d_ws, size_t ws_size,
                              hipStream_t stream) {
    const float* x = (const float*)d_in[0];
    const float* W = (const float*)d_in[1];
    const float* b = (const float*)d_in[2];
    float* out = (float*)d_out;                        // 131072*128 + 1 floats

    __hip_bfloat16* Wt = (__hip_bfloat16*)d_ws;                 // 128 KB
    double* partials = (double*)((char*)d_ws + 131072);         // 8 KB

    wt_prep_kernel<<<256, 256, 0, stream>>>(W, Wt);
    gemm_relu_mmd_kernel<<<GBLOCKS, 256, 0, stream>>>(x, Wt, b, out, partials);
    mmd_reduce_kernel<<<1, 256, 0, stream>>>(partials, out + (long)M_TOTAL * N_DIM);
}